// Round 2
// baseline (395.082 us; speedup 1.0000x reference)
//
#include <hip/hip_runtime.h>
#include <hip/hip_bf16.h>

#define H_DIM 2048
#define LN_EPS 1e-5f

typedef __bf16 bf16_t;
typedef __bf16 bf16x4 __attribute__((ext_vector_type(4)));
typedef __bf16 bf16x8 __attribute__((ext_vector_type(8)));
typedef float f32x4 __attribute__((ext_vector_type(4)));

// ---------------- async global->LDS helper (16B, wave-uniform LDS base) ----
__device__ __forceinline__ void async_copy16(const void* g, void* l) {
    __builtin_amdgcn_global_load_lds((const __attribute__((address_space(1))) void*)g,
                                     (__attribute__((address_space(3))) void*)l,
                                     16, 0, 0);
}

// ---------------- cast fp32 weights -> bf16 -------------------------------
__global__ __launch_bounds__(256) void cast_w_kernel(const float* __restrict__ w,
                                                     bf16_t* __restrict__ o, int n4) {
    int i = blockIdx.x * 256 + threadIdx.x;
    if (i < n4) {
        float4 v = reinterpret_cast<const float4*>(w)[i];
        bf16x4 r;
        r[0] = (bf16_t)v.x; r[1] = (bf16_t)v.y; r[2] = (bf16_t)v.z; r[3] = (bf16_t)v.w;
        reinterpret_cast<bf16x4*>(o)[i] = r;
    }
}

// ---------------- LayerNorm, fp32 input -> bf16 output --------------------
__global__ __launch_bounds__(256) void ln_f32_kernel(const float* __restrict__ in,
                                                     const float* __restrict__ g,
                                                     const float* __restrict__ b,
                                                     bf16_t* __restrict__ out) {
    const int row = blockIdx.x, t = threadIdx.x;
    const float* xr = in + (size_t)row * H_DIM;
    float4 v0 = reinterpret_cast<const float4*>(xr)[t * 2];
    float4 v1 = reinterpret_cast<const float4*>(xr)[t * 2 + 1];
    float v[8] = {v0.x, v0.y, v0.z, v0.w, v1.x, v1.y, v1.z, v1.w};
    float s = 0.f, s2 = 0.f;
    #pragma unroll
    for (int j = 0; j < 8; ++j) { s += v[j]; s2 += v[j] * v[j]; }
    #pragma unroll
    for (int off = 32; off > 0; off >>= 1) {
        s  += __shfl_down(s,  off, 64);
        s2 += __shfl_down(s2, off, 64);
    }
    __shared__ float red[8];
    int lane = t & 63, wid = t >> 6;
    if (lane == 0) { red[wid] = s; red[4 + wid] = s2; }
    __syncthreads();
    s  = red[0] + red[1] + red[2] + red[3];
    s2 = red[4] + red[5] + red[6] + red[7];
    float mu   = s * (1.f / H_DIM);
    float rstd = rsqrtf(s2 * (1.f / H_DIM) - mu * mu + LN_EPS);
    bf16x8 y;
    #pragma unroll
    for (int j = 0; j < 8; ++j) {
        y[j] = (bf16_t)((v[j] - mu) * rstd * g[t * 8 + j] + b[t * 8 + j]);
    }
    reinterpret_cast<bf16x8*>(out + (size_t)row * H_DIM)[t] = y;
}

// ---------------- LayerNorm, bf16 input -> bf16 output --------------------
__global__ __launch_bounds__(256) void ln_bf16_kernel(const bf16_t* __restrict__ in,
                                                      const float* __restrict__ g,
                                                      const float* __restrict__ b,
                                                      bf16_t* __restrict__ out) {
    const int row = blockIdx.x, t = threadIdx.x;
    bf16x8 xv = reinterpret_cast<const bf16x8*>(in + (size_t)row * H_DIM)[t];
    float v[8];
    #pragma unroll
    for (int j = 0; j < 8; ++j) v[j] = (float)xv[j];
    float s = 0.f, s2 = 0.f;
    #pragma unroll
    for (int j = 0; j < 8; ++j) { s += v[j]; s2 += v[j] * v[j]; }
    #pragma unroll
    for (int off = 32; off > 0; off >>= 1) {
        s  += __shfl_down(s,  off, 64);
        s2 += __shfl_down(s2, off, 64);
    }
    __shared__ float red[8];
    int lane = t & 63, wid = t >> 6;
    if (lane == 0) { red[wid] = s; red[4 + wid] = s2; }
    __syncthreads();
    s  = red[0] + red[1] + red[2] + red[3];
    s2 = red[4] + red[5] + red[6] + red[7];
    float mu   = s * (1.f / H_DIM);
    float rstd = rsqrtf(s2 * (1.f / H_DIM) - mu * mu + LN_EPS);
    bf16x8 y;
    #pragma unroll
    for (int j = 0; j < 8; ++j) {
        y[j] = (bf16_t)((v[j] - mu) * rstd * g[t * 8 + j] + b[t * 8 + j]);
    }
    reinterpret_cast<bf16x8*>(out + (size_t)row * H_DIM)[t] = y;
}

// ---------------- bf16 GEMM (B^T layout): C[i][j] = sum_k A[i,k]*B[j,k] ---
// m97 structure: 128x128 tile, BK=32, 4 waves (2x2), each wave 64x64 out,
// 4x4 fragments of mfma_f32_16x16x32_bf16, global_load_lds width=16 staging.
#define BM 128
#define BN 128
#define BK 32

template<int FINAL>
__global__ __launch_bounds__(256) void gemm_kernel(
    const bf16_t* __restrict__ A,    // [M][K] bf16 row-major
    const bf16_t* __restrict__ B,    // [N][K] bf16 row-major (weight)
    const float*  __restrict__ bias, // [N]
    const float*  __restrict__ resid,// [M][N] fp32 (x) or nullptr
    bf16_t* __restrict__ obf,        // bf16 output (FINAL=0)
    float*  __restrict__ of,         // fp32 output (FINAL=1)
    int M, int N, int K)
{
    __shared__ bf16_t As[BM * BK];
    __shared__ bf16_t Bs[BN * BK];
    const int t = threadIdx.x;
    const int lane = t & 63, wid = t >> 6;
    const int wr = wid >> 1, wc = wid & 1;      // 2x2 wave grid
    const int cl = lane & 15, ch = lane >> 4;
    const size_t row0 = (size_t)blockIdx.x * BM;
    const size_t col0 = (size_t)blockIdx.y * BN;

    f32x4 acc[4][4] = {};

    for (int k0 = 0; k0 < K; k0 += BK) {
        // stage A and B tiles: 128x32 bf16 each = 8KB; 2 issues x 256thr x 16B
        #pragma unroll
        for (int i = 0; i < 2; ++i) {
            int off = (i * 256 + t) * 8;        // element offset within tile
            int r = off >> 5;                   // /BK
            int c = off & 31;                   // %BK
            const bf16_t* ga = A + (row0 + r) * (size_t)K + k0 + c;
            const bf16_t* gb = B + (col0 + r) * (size_t)K + k0 + c;
            bf16_t* la = As + (size_t)(i * 256 + wid * 64) * 8;   // wave-uniform base
            bf16_t* lb = Bs + (size_t)(i * 256 + wid * 64) * 8;
            async_copy16(ga, la);
            async_copy16(gb, lb);
        }
        __syncthreads();

        bf16x8 af[4], bfr[4];
        #pragma unroll
        for (int m = 0; m < 4; ++m)
            af[m] = *reinterpret_cast<const bf16x8*>(&As[(wr * 64 + m * 16 + cl) * BK + ch * 8]);
        #pragma unroll
        for (int n = 0; n < 4; ++n)
            bfr[n] = *reinterpret_cast<const bf16x8*>(&Bs[(wc * 64 + n * 16 + cl) * BK + ch * 8]);
        #pragma unroll
        for (int m = 0; m < 4; ++m)
            #pragma unroll
            for (int n = 0; n < 4; ++n)
                acc[m][n] = __builtin_amdgcn_mfma_f32_16x16x32_bf16(af[m], bfr[n], acc[m][n], 0, 0, 0);
        __syncthreads();
    }

    // epilogue: C/D mapping col=lane&15, row=(lane>>4)*4+reg (m89-verified)
    #pragma unroll
    for (int m = 0; m < 4; ++m) {
        #pragma unroll
        for (int n = 0; n < 4; ++n) {
            size_t col = col0 + wc * 64 + n * 16 + cl;
            float bv = bias[col];
            #pragma unroll
            for (int j = 0; j < 4; ++j) {
                size_t row = row0 + wr * 64 + m * 16 + ch * 4 + j;
                size_t idx = row * (size_t)N + col;
                float v = acc[m][n][j] + bv;
                if constexpr (FINAL) {
                    v += resid[idx];
                    of[idx] = fmaxf(v, 0.f);
                } else {
                    obf[idx] = (bf16_t)fmaxf(v, 0.f);
                }
            }
        }
    }
}

extern "C" void kernel_launch(void* const* d_in, const int* in_sizes, int n_in,
                              void* d_out, int out_size, void* d_ws, size_t ws_size,
                              hipStream_t stream) {
    const float* x   = (const float*)d_in[0];
    const float* W1  = (const float*)d_in[1];
    const float* b1  = (const float*)d_in[2];
    const float* W2  = (const float*)d_in[3];
    const float* b2  = (const float*)d_in[4];
    const float* g1  = (const float*)d_in[5];
    const float* be1 = (const float*)d_in[6];
    const float* g2  = (const float*)d_in[7];
    const float* be2 = (const float*)d_in[8];
    float* out = (float*)d_out;

    const int M = in_sizes[0] / H_DIM;   // 8192
    const int N = H_DIM, K = H_DIM;

    char* ws = (char*)d_ws;
    bf16_t* W1b = (bf16_t*)(ws);                          //  8 MiB
    bf16_t* W2b = (bf16_t*)(ws + (8u << 20));             //  8 MiB
    bf16_t* lnb = (bf16_t*)(ws + (16u << 20));            // 32 MiB (ln1 out, reused for ln2 out)
    bf16_t* h1  = (bf16_t*)(ws + (48u << 20));            // 32 MiB

    const int wn4 = (H_DIM * H_DIM) / 4;                  // 1048576
    cast_w_kernel<<<dim3((wn4 + 255) / 256), dim3(256), 0, stream>>>(W1, W1b, wn4);
    cast_w_kernel<<<dim3((wn4 + 255) / 256), dim3(256), 0, stream>>>(W2, W2b, wn4);

    // ln1: x -> lnb (bf16)
    ln_f32_kernel<<<dim3(M), dim3(256), 0, stream>>>(x, g1, be1, lnb);

    // h1 = relu(lnb @ W1^T + b1) -> bf16
    gemm_kernel<0><<<dim3(M / BM, N / BN), dim3(256), 0, stream>>>(
        lnb, W1b, b1, nullptr, h1, nullptr, M, N, K);

    // ln2: h1 -> lnb (bf16)
    ln_bf16_kernel<<<dim3(M), dim3(256), 0, stream>>>(h1, g2, be2, lnb);

    // out = relu(lnb @ W2^T + b2 + x) -> fp32
    gemm_kernel<1><<<dim3(M / BM, N / BN), dim3(256), 0, stream>>>(
        lnb, W2b, b2, x, nullptr, out, M, N, K);
}

// Round 3
// 309.572 us; speedup vs baseline: 1.2762x; 1.2762x over previous
//
#include <hip/hip_runtime.h>
#include <hip/hip_bf16.h>

#define H_DIM 2048
#define LN_EPS 1e-5f

typedef __bf16 bf16_t;
typedef __bf16 bf16x4 __attribute__((ext_vector_type(4)));
typedef __bf16 bf16x8 __attribute__((ext_vector_type(8)));
typedef float f32x4 __attribute__((ext_vector_type(4)));

__device__ __forceinline__ void async_copy16(const void* g, void* l) {
    __builtin_amdgcn_global_load_lds((const __attribute__((address_space(1))) void*)g,
                                     (__attribute__((address_space(3))) void*)l,
                                     16, 0, 0);
}

#define FENCE() asm volatile("" ::: "memory")
#define BARRIER() do { FENCE(); __builtin_amdgcn_s_barrier(); FENCE(); } while (0)

// ---------------- cast fp32 weights -> bf16 -------------------------------
__global__ __launch_bounds__(256) void cast_w_kernel(const float* __restrict__ w,
                                                     bf16_t* __restrict__ o, int n4) {
    int i = blockIdx.x * 256 + threadIdx.x;
    if (i < n4) {
        float4 v = reinterpret_cast<const float4*>(w)[i];
        bf16x4 r;
        r[0] = (bf16_t)v.x; r[1] = (bf16_t)v.y; r[2] = (bf16_t)v.z; r[3] = (bf16_t)v.w;
        reinterpret_cast<bf16x4*>(o)[i] = r;
    }
}

// ---------------- LayerNorm v2: one WAVE per row (no block sync) ----------
__global__ __launch_bounds__(256) void ln_f32_v2(const float* __restrict__ in,
                                                 const float* __restrict__ g,
                                                 const float* __restrict__ b,
                                                 bf16_t* __restrict__ out) {
    const int l = threadIdx.x & 63, w = threadIdx.x >> 6;
    const size_t row = (size_t)blockIdx.x * 4 + w;
    const float* xr = in + row * H_DIM;
    float4 v[8];
    #pragma unroll
    for (int k = 0; k < 8; ++k) v[k] = reinterpret_cast<const float4*>(xr)[l + k * 64];
    float s = 0.f, s2 = 0.f;
    #pragma unroll
    for (int k = 0; k < 8; ++k) {
        s  += v[k].x + v[k].y + v[k].z + v[k].w;
        s2 += v[k].x * v[k].x + v[k].y * v[k].y + v[k].z * v[k].z + v[k].w * v[k].w;
    }
    #pragma unroll
    for (int off = 32; off > 0; off >>= 1) {
        s  += __shfl_down(s,  off, 64);
        s2 += __shfl_down(s2, off, 64);
    }
    s  = __shfl(s,  0, 64);
    s2 = __shfl(s2, 0, 64);
    float mu   = s * (1.f / H_DIM);
    float rstd = rsqrtf(s2 * (1.f / H_DIM) - mu * mu + LN_EPS);
    bf16_t* orow = out + row * H_DIM;
    #pragma unroll
    for (int k = 0; k < 8; ++k) {
        int c = l + k * 64;
        float4 gv = reinterpret_cast<const float4*>(g)[c];
        float4 bv = reinterpret_cast<const float4*>(b)[c];
        bf16x4 y;
        y[0] = (bf16_t)((v[k].x - mu) * rstd * gv.x + bv.x);
        y[1] = (bf16_t)((v[k].y - mu) * rstd * gv.y + bv.y);
        y[2] = (bf16_t)((v[k].z - mu) * rstd * gv.z + bv.z);
        y[3] = (bf16_t)((v[k].w - mu) * rstd * gv.w + bv.w);
        reinterpret_cast<bf16x4*>(orow)[c] = y;
    }
}

__global__ __launch_bounds__(256) void ln_bf16_v2(const bf16_t* __restrict__ in,
                                                  const float* __restrict__ g,
                                                  const float* __restrict__ b,
                                                  bf16_t* __restrict__ out) {
    const int l = threadIdx.x & 63, w = threadIdx.x >> 6;
    const size_t row = (size_t)blockIdx.x * 4 + w;
    const bf16_t* xr = in + row * H_DIM;
    bf16x8 xv[4];
    #pragma unroll
    for (int k = 0; k < 4; ++k) xv[k] = reinterpret_cast<const bf16x8*>(xr)[l + k * 64];
    float vv[32];
    #pragma unroll
    for (int k = 0; k < 4; ++k)
        #pragma unroll
        for (int j = 0; j < 8; ++j) vv[k * 8 + j] = (float)xv[k][j];
    float s = 0.f, s2 = 0.f;
    #pragma unroll
    for (int e = 0; e < 32; ++e) { s += vv[e]; s2 += vv[e] * vv[e]; }
    #pragma unroll
    for (int off = 32; off > 0; off >>= 1) {
        s  += __shfl_down(s,  off, 64);
        s2 += __shfl_down(s2, off, 64);
    }
    s  = __shfl(s,  0, 64);
    s2 = __shfl(s2, 0, 64);
    float mu   = s * (1.f / H_DIM);
    float rstd = rsqrtf(s2 * (1.f / H_DIM) - mu * mu + LN_EPS);
    bf16_t* orow = out + row * H_DIM;
    #pragma unroll
    for (int k = 0; k < 4; ++k) {
        int c = l + k * 64;                       // 16B chunk index (8 elems)
        float4 g0 = reinterpret_cast<const float4*>(g)[c * 2];
        float4 g1 = reinterpret_cast<const float4*>(g)[c * 2 + 1];
        float4 b0 = reinterpret_cast<const float4*>(b)[c * 2];
        float4 b1 = reinterpret_cast<const float4*>(b)[c * 2 + 1];
        bf16x8 y;
        y[0] = (bf16_t)((vv[k*8+0] - mu) * rstd * g0.x + b0.x);
        y[1] = (bf16_t)((vv[k*8+1] - mu) * rstd * g0.y + b0.y);
        y[2] = (bf16_t)((vv[k*8+2] - mu) * rstd * g0.z + b0.z);
        y[3] = (bf16_t)((vv[k*8+3] - mu) * rstd * g0.w + b0.w);
        y[4] = (bf16_t)((vv[k*8+4] - mu) * rstd * g1.x + b1.x);
        y[5] = (bf16_t)((vv[k*8+5] - mu) * rstd * g1.y + b1.y);
        y[6] = (bf16_t)((vv[k*8+6] - mu) * rstd * g1.z + b1.z);
        y[7] = (bf16_t)((vv[k*8+7] - mu) * rstd * g1.w + b1.w);
        reinterpret_cast<bf16x8*>(orow)[c] = y;
    }
}

// ---------------- 256x256 8-phase bf16 GEMM (B^T): C[i][j]=sum_k A[i,k]B[j,k]
// 8 waves (2M x 4N), BK=64, 128 KiB LDS double-buffer, XOR swizzle cb^=(r&7)
// applied on BOTH the pre-swizzled global source and the ds_read address.
// LDS regions (8 x 16KB): region = buf*4 + mat*2 + half  (mat: A=0,B=1).
template<int FINAL>
__global__ __launch_bounds__(512, 2) void gemm8_kernel(
    const bf16_t* __restrict__ A,    // [M][2048] bf16
    const bf16_t* __restrict__ B,    // [2048][2048] bf16 (weight, row=out col)
    const float*  __restrict__ bias,
    const float*  __restrict__ resid,
    bf16_t* __restrict__ obf,
    float*  __restrict__ of)
{
    __shared__ bf16_t sm[8 * 8192];   // 128 KiB

    const int tid = threadIdx.x;
    const int l  = tid & 63, w = tid >> 6;
    const int wm = w >> 2,  wn = w & 3;          // 2 x 4 wave grid
    const int cl = l & 15,  ch = l >> 4;

    // T1: bijective XCD swizzle (gridDim.x % 8 == 0 here: 256)
    const int cpx = gridDim.x >> 3;
    const int bid = blockIdx.x;
    const int swz = (bid & 7) * cpx + (bid >> 3);
    const size_t row0 = (size_t)(swz >> 3) * 256;
    const size_t col0 = (size_t)(swz & 7) * 256;

    const bf16_t* Abase = A + row0 * H_DIM;
    const bf16_t* Bbase = B + col0 * H_DIM;

    // staging: chunk c = i*512 + w*64 + l; r=c>>3, cb=c&7; src col-block = cb^(r&7)
    const int rr  = w * 8 + (l >> 3);            // row within 64-row slab (r&7 = l>>3)
    const int scb = (l & 7) ^ (l >> 3);
    const size_t soff  = (size_t)rr * H_DIM + scb * 8;
    const int ldsw0 = w * 512;                   // elems; issue 1 at +4096
    const int ldsw1 = 4096 + w * 512;

    // read-side swizzled col-blocks (r&7 == cl&7 for all fragment rows)
    const int swx = cl & 7;
    const int cbks[2] = { ch ^ swx, (4 + ch) ^ swx };

    f32x4 acc[2][4][4] = {};

    auto STAGE = [&](const bf16_t* Gb, int kt, int half, int region) {
        const bf16_t* g = Gb + (size_t)half * (128 * H_DIM) + kt * 64 + soff;
        bf16_t* s = &sm[region * 8192];
        async_copy16(g,               s + ldsw0);
        async_copy16(g + 64 * H_DIM,  s + ldsw1);
    };
    auto RDA = [&](int buf, int mh, int m, int ks) -> bf16x8 {
        int r = mh * 64 + m * 16 + cl;
        return *(const bf16x8*)&sm[(buf * 4 + wm) * 8192 + r * 64 + cbks[ks] * 8];
    };
    auto RDB = [&](int buf, int n, int ks) -> bf16x8 {
        int r = (wn & 1) * 64 + n * 16 + cl;
        return *(const bf16x8*)&sm[(buf * 4 + 2 + (wn >> 1)) * 8192 + r * 64 + cbks[ks] * 8];
    };

    auto KTILE = [&](int t, bool stA, bool stB, int vm) {
        const int buf = t & 1;
        bf16x8 a[4], b0[4], b1[4];
        // ---- P1: read B(ks0)+B(ks1)+A(mh0,ks0) [12]; stage A(t+1,h0)->buf^1
        #pragma unroll
        for (int n = 0; n < 4; ++n) { b0[n] = RDB(buf, n, 0); b1[n] = RDB(buf, n, 1); }
        #pragma unroll
        for (int m = 0; m < 4; ++m) a[m] = RDA(buf, 0, m, 0);
        if (stA) STAGE(Abase, t + 1, 0, ((t + 1) & 1) * 4 + 0);
        BARRIER();
        __builtin_amdgcn_s_setprio(1);
        #pragma unroll
        for (int m = 0; m < 4; ++m)
            #pragma unroll
            for (int n = 0; n < 4; ++n)
                acc[0][m][n] = __builtin_amdgcn_mfma_f32_16x16x32_bf16(a[m], b0[n], acc[0][m][n], 0, 0, 0);
        __builtin_amdgcn_s_setprio(0);
        BARRIER();
        // ---- P2: read A(mh0,ks1) [4]; stage A(t+1,h1)->buf^1
        #pragma unroll
        for (int m = 0; m < 4; ++m) a[m] = RDA(buf, 0, m, 1);
        if (stA) STAGE(Abase, t + 1, 1, ((t + 1) & 1) * 4 + 1);
        BARRIER();
        __builtin_amdgcn_s_setprio(1);
        #pragma unroll
        for (int m = 0; m < 4; ++m)
            #pragma unroll
            for (int n = 0; n < 4; ++n)
                acc[0][m][n] = __builtin_amdgcn_mfma_f32_16x16x32_bf16(a[m], b1[n], acc[0][m][n], 0, 0, 0);
        __builtin_amdgcn_s_setprio(0);
        BARRIER();
        // ---- P3: read A(mh1,ks0) [4]; stage B(t+2,h0)->buf (B0(t) reads done in P1)
        #pragma unroll
        for (int m = 0; m < 4; ++m) a[m] = RDA(buf, 1, m, 0);
        if (stB) STAGE(Bbase, t + 2, 0, buf * 4 + 2);
        BARRIER();
        __builtin_amdgcn_s_setprio(1);
        #pragma unroll
        for (int m = 0; m < 4; ++m)
            #pragma unroll
            for (int n = 0; n < 4; ++n)
                acc[1][m][n] = __builtin_amdgcn_mfma_f32_16x16x32_bf16(a[m], b0[n], acc[1][m][n], 0, 0, 0);
        __builtin_amdgcn_s_setprio(0);
        BARRIER();
        // ---- P4: read A(mh1,ks1) [4]; stage B(t+2,h1)->buf; counted vmcnt
        #pragma unroll
        for (int m = 0; m < 4; ++m) a[m] = RDA(buf, 1, m, 1);
        if (stB) STAGE(Bbase, t + 2, 1, buf * 4 + 3);
        BARRIER();
        __builtin_amdgcn_s_setprio(1);
        #pragma unroll
        for (int m = 0; m < 4; ++m)
            #pragma unroll
            for (int n = 0; n < 4; ++n)
                acc[1][m][n] = __builtin_amdgcn_mfma_f32_16x16x32_bf16(a[m], b1[n], acc[1][m][n], 0, 0, 0);
        __builtin_amdgcn_s_setprio(0);
        if (vm == 4)      asm volatile("s_waitcnt vmcnt(4)");
        else if (vm == 0) asm volatile("s_waitcnt vmcnt(0)");
        BARRIER();
    };

    // prologue: K-tile 0 fully + B halves of K-tile 1 (their slot is t=-1)
    STAGE(Abase, 0, 0, 0); STAGE(Abase, 0, 1, 1);
    STAGE(Bbase, 0, 0, 2); STAGE(Bbase, 0, 1, 3);
    STAGE(Bbase, 1, 0, 6); STAGE(Bbase, 1, 1, 7);
    asm volatile("s_waitcnt vmcnt(4)");   // K0's 8 per-wave... per-wave: 12 issued, oldest 8 (K0) done
    BARRIER();

    const int NT = H_DIM / 64;            // 32
    for (int t = 0; t < NT - 2; ++t) KTILE(t, true, true, 4);
    KTILE(NT - 2, true, false, 0);
    KTILE(NT - 1, false, false, -1);

    // epilogue: C/D map col=cl, row=ch*4+j (m89-verified, same as round 0)
    #pragma unroll
    for (int mh = 0; mh < 2; ++mh)
        #pragma unroll
        for (int m = 0; m < 4; ++m)
            #pragma unroll
            for (int n = 0; n < 4; ++n) {
                size_t col = col0 + wn * 64 + n * 16 + cl;
                float bv = bias[col];
                #pragma unroll
                for (int j = 0; j < 4; ++j) {
                    size_t row = row0 + wm * 128 + mh * 64 + m * 16 + ch * 4 + j;
                    size_t idx = row * H_DIM + col;
                    float v = acc[mh][m][n][j] + bv;
                    if constexpr (FINAL) {
                        v += resid[idx];
                        of[idx] = fmaxf(v, 0.f);
                    } else {
                        obf[idx] = (bf16_t)fmaxf(v, 0.f);
                    }
                }
            }
}

extern "C" void kernel_launch(void* const* d_in, const int* in_sizes, int n_in,
                              void* d_out, int out_size, void* d_ws, size_t ws_size,
                              hipStream_t stream) {
    const float* x   = (const float*)d_in[0];
    const float* W1  = (const float*)d_in[1];
    const float* b1  = (const float*)d_in[2];
    const float* W2  = (const float*)d_in[3];
    const float* b2  = (const float*)d_in[4];
    const float* g1  = (const float*)d_in[5];
    const float* be1 = (const float*)d_in[6];
    const float* g2  = (const float*)d_in[7];
    const float* be2 = (const float*)d_in[8];
    float* out = (float*)d_out;

    const int M = in_sizes[0] / H_DIM;   // 8192

    char* ws = (char*)d_ws;
    bf16_t* W1b = (bf16_t*)(ws);
    bf16_t* W2b = (bf16_t*)(ws + (8u << 20));
    bf16_t* lnb = (bf16_t*)(ws + (16u << 20));
    bf16_t* h1  = (bf16_t*)(ws + (48u << 20));

    const int wn4 = (H_DIM * H_DIM) / 4;
    cast_w_kernel<<<dim3((wn4 + 255) / 256), dim3(256), 0, stream>>>(W1, W1b, wn4);
    cast_w_kernel<<<dim3((wn4 + 255) / 256), dim3(256), 0, stream>>>(W2, W2b, wn4);

    ln_f32_v2<<<dim3(M / 4), dim3(256), 0, stream>>>(x, g1, be1, lnb);

    gemm8_kernel<0><<<dim3((M / 256) * 8), dim3(512), 0, stream>>>(
        lnb, W1b, b1, nullptr, h1, nullptr);

    ln_bf16_v2<<<dim3(M / 4), dim3(256), 0, stream>>>(h1, g2, be2, lnb);

    gemm8_kernel<1><<<dim3((M / 256) * 8), dim3(512), 0, stream>>>(
        lnb, W2b, b2, x, nullptr, out);
}

// Round 4
// 302.686 us; speedup vs baseline: 1.3053x; 1.0227x over previous
//
#include <hip/hip_runtime.h>
#include <hip/hip_bf16.h>

#define H_DIM 2048
#define LN_EPS 1e-5f

typedef __bf16 bf16_t;
typedef __bf16 bf16x4 __attribute__((ext_vector_type(4)));
typedef __bf16 bf16x8 __attribute__((ext_vector_type(8)));
typedef float f32x4 __attribute__((ext_vector_type(4)));

__device__ __forceinline__ void async_copy16(const void* g, void* l) {
    __builtin_amdgcn_global_load_lds((const __attribute__((address_space(1))) void*)g,
                                     (__attribute__((address_space(3))) void*)l,
                                     16, 0, 0);
}

#define FENCE() asm volatile("" ::: "memory")
#define BARRIER() do { FENCE(); __builtin_amdgcn_s_barrier(); FENCE(); } while (0)

// ---------------- fused cast fp32 -> bf16 for both weights ----------------
__global__ __launch_bounds__(256) void cast2_kernel(const float* __restrict__ w1,
                                                    const float* __restrict__ w2,
                                                    bf16_t* __restrict__ o1,
                                                    bf16_t* __restrict__ o2) {
    const int n4 = (H_DIM * H_DIM) / 4;
    int i = blockIdx.x * 256 + threadIdx.x;
    const float* src; bf16_t* dst; int j;
    if (i < n4) { src = w1; dst = o1; j = i; }
    else        { src = w2; dst = o2; j = i - n4; }
    float4 v = reinterpret_cast<const float4*>(src)[j];
    bf16x4 r;
    r[0] = (bf16_t)v.x; r[1] = (bf16_t)v.y; r[2] = (bf16_t)v.z; r[3] = (bf16_t)v.w;
    reinterpret_cast<bf16x4*>(dst)[j] = r;
}

// ---------------- LayerNorm: one WAVE per row; optionally emits bf16 x ----
__global__ __launch_bounds__(256) void ln_f32_v2(const float* __restrict__ in,
                                                 const float* __restrict__ g,
                                                 const float* __restrict__ b,
                                                 bf16_t* __restrict__ out,
                                                 bf16_t* __restrict__ xb) {
    const int l = threadIdx.x & 63, w = threadIdx.x >> 6;
    const size_t row = (size_t)blockIdx.x * 4 + w;
    const float* xr = in + row * H_DIM;
    float4 v[8];
    #pragma unroll
    for (int k = 0; k < 8; ++k) v[k] = reinterpret_cast<const float4*>(xr)[l + k * 64];
    float s = 0.f, s2 = 0.f;
    #pragma unroll
    for (int k = 0; k < 8; ++k) {
        s  += v[k].x + v[k].y + v[k].z + v[k].w;
        s2 += v[k].x * v[k].x + v[k].y * v[k].y + v[k].z * v[k].z + v[k].w * v[k].w;
    }
    #pragma unroll
    for (int off = 32; off > 0; off >>= 1) {
        s  += __shfl_down(s,  off, 64);
        s2 += __shfl_down(s2, off, 64);
    }
    s  = __shfl(s,  0, 64);
    s2 = __shfl(s2, 0, 64);
    float mu   = s * (1.f / H_DIM);
    float rstd = rsqrtf(s2 * (1.f / H_DIM) - mu * mu + LN_EPS);
    bf16_t* orow = out + row * H_DIM;
    bf16_t* xrow = xb ? xb + row * H_DIM : nullptr;
    #pragma unroll
    for (int k = 0; k < 8; ++k) {
        int c = l + k * 64;
        float4 gv = reinterpret_cast<const float4*>(g)[c];
        float4 bv = reinterpret_cast<const float4*>(b)[c];
        bf16x4 y;
        y[0] = (bf16_t)((v[k].x - mu) * rstd * gv.x + bv.x);
        y[1] = (bf16_t)((v[k].y - mu) * rstd * gv.y + bv.y);
        y[2] = (bf16_t)((v[k].z - mu) * rstd * gv.z + bv.z);
        y[3] = (bf16_t)((v[k].w - mu) * rstd * gv.w + bv.w);
        reinterpret_cast<bf16x4*>(orow)[c] = y;
        if (xrow) {
            bf16x4 xv;
            xv[0] = (bf16_t)v[k].x; xv[1] = (bf16_t)v[k].y;
            xv[2] = (bf16_t)v[k].z; xv[3] = (bf16_t)v[k].w;
            reinterpret_cast<bf16x4*>(xrow)[c] = xv;
        }
    }
}

__global__ __launch_bounds__(256) void ln_bf16_v2(const bf16_t* __restrict__ in,
                                                  const float* __restrict__ g,
                                                  const float* __restrict__ b,
                                                  bf16_t* __restrict__ out) {
    const int l = threadIdx.x & 63, w = threadIdx.x >> 6;
    const size_t row = (size_t)blockIdx.x * 4 + w;
    const bf16_t* xr = in + row * H_DIM;
    bf16x8 xv[4];
    #pragma unroll
    for (int k = 0; k < 4; ++k) xv[k] = reinterpret_cast<const bf16x8*>(xr)[l + k * 64];
    float vv[32];
    #pragma unroll
    for (int k = 0; k < 4; ++k)
        #pragma unroll
        for (int j = 0; j < 8; ++j) vv[k * 8 + j] = (float)xv[k][j];
    float s = 0.f, s2 = 0.f;
    #pragma unroll
    for (int e = 0; e < 32; ++e) { s += vv[e]; s2 += vv[e] * vv[e]; }
    #pragma unroll
    for (int off = 32; off > 0; off >>= 1) {
        s  += __shfl_down(s,  off, 64);
        s2 += __shfl_down(s2, off, 64);
    }
    s  = __shfl(s,  0, 64);
    s2 = __shfl(s2, 0, 64);
    float mu   = s * (1.f / H_DIM);
    float rstd = rsqrtf(s2 * (1.f / H_DIM) - mu * mu + LN_EPS);
    bf16_t* orow = out + row * H_DIM;
    #pragma unroll
    for (int k = 0; k < 4; ++k) {
        int c = l + k * 64;
        float4 g0 = reinterpret_cast<const float4*>(g)[c * 2];
        float4 g1 = reinterpret_cast<const float4*>(g)[c * 2 + 1];
        float4 b0 = reinterpret_cast<const float4*>(b)[c * 2];
        float4 b1 = reinterpret_cast<const float4*>(b)[c * 2 + 1];
        bf16x8 y;
        y[0] = (bf16_t)((vv[k*8+0] - mu) * rstd * g0.x + b0.x);
        y[1] = (bf16_t)((vv[k*8+1] - mu) * rstd * g0.y + b0.y);
        y[2] = (bf16_t)((vv[k*8+2] - mu) * rstd * g0.z + b0.z);
        y[3] = (bf16_t)((vv[k*8+3] - mu) * rstd * g0.w + b0.w);
        y[4] = (bf16_t)((vv[k*8+4] - mu) * rstd * g1.x + b1.x);
        y[5] = (bf16_t)((vv[k*8+5] - mu) * rstd * g1.y + b1.y);
        y[6] = (bf16_t)((vv[k*8+6] - mu) * rstd * g1.z + b1.z);
        y[7] = (bf16_t)((vv[k*8+7] - mu) * rstd * g1.w + b1.w);
        reinterpret_cast<bf16x8*>(orow)[c] = y;
    }
}

// ---------------- 256x256 8-wave 4-phase bf16 GEMM (B^T) ------------------
// K-loop unrolled x2 so buf is a literal -> hoisted LDS bases, imm offsets.
// FINAL: 0 = bf16 out via LDS-bounce coalesced store; 1 = fp32 out + resid.
// RB: resid is bf16 (xb) if 1, fp32 if 0.
#define LDW 88   // bounce pitch (176B rows: 16B-aligned, conflict-light)

template<int FINAL, int RB>
__global__ __launch_bounds__(512, 2) void gemm8_kernel(
    const bf16_t* __restrict__ A,
    const bf16_t* __restrict__ B,
    const float*  __restrict__ bias,
    const float*  __restrict__ residf,
    const bf16_t* __restrict__ residb,
    bf16_t* __restrict__ obf,
    float*  __restrict__ of)
{
    __shared__ bf16_t sm[8 * 8192];   // 128 KiB

    const int tid = threadIdx.x;
    const int l  = tid & 63, w = tid >> 6;
    const int wm = w >> 2,  wn = w & 3;
    const int cl = l & 15,  ch = l >> 4;

    const int cpx = gridDim.x >> 3;
    const int bid = blockIdx.x;
    const int swz = (bid & 7) * cpx + (bid >> 3);
    const size_t row0 = (size_t)(swz >> 3) * 256;
    const size_t col0 = (size_t)(swz & 7) * 256;

    const bf16_t* Abase = A + row0 * H_DIM;
    const bf16_t* Bbase = B + col0 * H_DIM;

    const int rr  = w * 8 + (l >> 3);
    const int scb = (l & 7) ^ (l >> 3);
    const size_t soff  = (size_t)rr * H_DIM + scb * 8;
    const int ldsw0 = w * 512;
    const int ldsw1 = 4096 + w * 512;

    const int swx = cl & 7;
    const int cbks[2] = { ch ^ swx, (4 + ch) ^ swx };

    f32x4 acc[2][4][4] = {};

    auto STAGE = [&](const bf16_t* Gb, int kt, int half, int region) {
        const bf16_t* g = Gb + (size_t)half * (128 * H_DIM) + kt * 64 + soff;
        bf16_t* s = &sm[region * 8192];
        async_copy16(g,               s + ldsw0);
        async_copy16(g + 64 * H_DIM,  s + ldsw1);
    };
    auto RDA = [&](int buf, int mh, int m, int ks) -> bf16x8 {
        int r = mh * 64 + m * 16 + cl;
        return *(const bf16x8*)&sm[(buf * 4 + wm) * 8192 + r * 64 + cbks[ks] * 8];
    };
    auto RDB = [&](int buf, int n, int ks) -> bf16x8 {
        int r = (wn & 1) * 64 + n * 16 + cl;
        return *(const bf16x8*)&sm[(buf * 4 + 2 + (wn >> 1)) * 8192 + r * 64 + cbks[ks] * 8];
    };

    // KT: buf MUST be a literal at each call site (loop unrolled x2).
    auto KT = [&](int buf, int t, bool stA, bool stB, int vm) {
        bf16x8 a[4], b0[4], b1[4];
        // P1: reads b0(4)+a(mh0,ks0)(4); stage A(t+1,h0)
        #pragma unroll
        for (int n = 0; n < 4; ++n) b0[n] = RDB(buf, n, 0);
        #pragma unroll
        for (int m = 0; m < 4; ++m) a[m] = RDA(buf, 0, m, 0);
        if (stA) STAGE(Abase, t + 1, 0, (buf ^ 1) * 4 + 0);
        BARRIER();
        __builtin_amdgcn_s_setprio(1);
        #pragma unroll
        for (int m = 0; m < 4; ++m)
            #pragma unroll
            for (int n = 0; n < 4; ++n)
                acc[0][m][n] = __builtin_amdgcn_mfma_f32_16x16x32_bf16(a[m], b0[n], acc[0][m][n], 0, 0, 0);
        __builtin_amdgcn_s_setprio(0);
        BARRIER();
        // P2: reads b1(4)+a(mh0,ks1)(4); stage A(t+1,h1)
        #pragma unroll
        for (int n = 0; n < 4; ++n) b1[n] = RDB(buf, n, 1);
        #pragma unroll
        for (int m = 0; m < 4; ++m) a[m] = RDA(buf, 0, m, 1);
        if (stA) STAGE(Abase, t + 1, 1, (buf ^ 1) * 4 + 1);
        BARRIER();
        __builtin_amdgcn_s_setprio(1);
        #pragma unroll
        for (int m = 0; m < 4; ++m)
            #pragma unroll
            for (int n = 0; n < 4; ++n)
                acc[0][m][n] = __builtin_amdgcn_mfma_f32_16x16x32_bf16(a[m], b1[n], acc[0][m][n], 0, 0, 0);
        __builtin_amdgcn_s_setprio(0);
        BARRIER();
        // P3: reads a(mh1,ks0)(4); stage B(t+2,h0)
        #pragma unroll
        for (int m = 0; m < 4; ++m) a[m] = RDA(buf, 1, m, 0);
        if (stB) STAGE(Bbase, t + 2, 0, buf * 4 + 2);
        BARRIER();
        __builtin_amdgcn_s_setprio(1);
        #pragma unroll
        for (int m = 0; m < 4; ++m)
            #pragma unroll
            for (int n = 0; n < 4; ++n)
                acc[1][m][n] = __builtin_amdgcn_mfma_f32_16x16x32_bf16(a[m], b0[n], acc[1][m][n], 0, 0, 0);
        __builtin_amdgcn_s_setprio(0);
        BARRIER();
        // P4: reads a(mh1,ks1)(4); stage B(t+2,h1); counted vmcnt
        #pragma unroll
        for (int m = 0; m < 4; ++m) a[m] = RDA(buf, 1, m, 1);
        if (stB) STAGE(Bbase, t + 2, 1, buf * 4 + 3);
        BARRIER();
        __builtin_amdgcn_s_setprio(1);
        #pragma unroll
        for (int m = 0; m < 4; ++m)
            #pragma unroll
            for (int n = 0; n < 4; ++n)
                acc[1][m][n] = __builtin_amdgcn_mfma_f32_16x16x32_bf16(a[m], b1[n], acc[1][m][n], 0, 0, 0);
        __builtin_amdgcn_s_setprio(0);
        if (vm == 4)      asm volatile("s_waitcnt vmcnt(4)");
        else if (vm == 0) asm volatile("s_waitcnt vmcnt(0)");
        BARRIER();
    };

    // prologue
    STAGE(Abase, 0, 0, 0); STAGE(Abase, 0, 1, 1);
    STAGE(Bbase, 0, 0, 2); STAGE(Bbase, 0, 1, 3);
    STAGE(Bbase, 1, 0, 6); STAGE(Bbase, 1, 1, 7);
    asm volatile("s_waitcnt vmcnt(4)");
    BARRIER();

    // K loop: NT = 32, unrolled x2 (buf literal)
    for (int t = 0; t < 30; t += 2) {
        KT(0, t,     true, true, 4);
        KT(1, t + 1, true, true, 4);
    }
    KT(0, 30, true,  false, 0);
    KT(1, 31, false, false, -1);

    // epilogue
    if constexpr (FINAL) {
        #pragma unroll
        for (int mh = 0; mh < 2; ++mh)
            #pragma unroll
            for (int m = 0; m < 4; ++m)
                #pragma unroll
                for (int n = 0; n < 4; ++n) {
                    size_t col = col0 + wn * 64 + n * 16 + cl;
                    float bv = bias[col];
                    #pragma unroll
                    for (int j = 0; j < 4; ++j) {
                        size_t row = row0 + wm * 128 + mh * 64 + m * 16 + ch * 4 + j;
                        size_t idx = row * H_DIM + col;
                        float rv = RB ? (float)residb[idx] : residf[idx];
                        of[idx] = fmaxf(acc[mh][m][n][j] + bv + rv, 0.f);
                    }
                }
    } else {
        // coalesced bf16 store via per-wave LDS bounce (2 passes, 64x88 each)
        bf16_t* wls = (bf16_t*)((char*)sm + w * (64 * LDW * 2));
        #pragma unroll
        for (int mh = 0; mh < 2; ++mh) {
            #pragma unroll
            for (int m = 0; m < 4; ++m)
                #pragma unroll
                for (int n = 0; n < 4; ++n) {
                    float bv = bias[col0 + wn * 64 + n * 16 + cl];
                    #pragma unroll
                    for (int j = 0; j < 4; ++j) {
                        int lr = m * 16 + ch * 4 + j;
                        int lc = n * 16 + cl;
                        wls[lr * LDW + lc] = (bf16_t)fmaxf(acc[mh][m][n][j] + bv, 0.f);
                    }
                }
            #pragma unroll
            for (int k = 0; k < 8; ++k) {
                int c = l + k * 64;
                int r = c >> 3, cb = c & 7;
                bf16x8 vv = *(const bf16x8*)&wls[r * LDW + cb * 8];
                size_t grow = row0 + wm * 128 + mh * 64 + r;
                *(bf16x8*)&obf[grow * H_DIM + col0 + wn * 64 + cb * 8] = vv;
            }
        }
    }
}

extern "C" void kernel_launch(void* const* d_in, const int* in_sizes, int n_in,
                              void* d_out, int out_size, void* d_ws, size_t ws_size,
                              hipStream_t stream) {
    const float* x   = (const float*)d_in[0];
    const float* W1  = (const float*)d_in[1];
    const float* b1  = (const float*)d_in[2];
    const float* W2  = (const float*)d_in[3];
    const float* b2  = (const float*)d_in[4];
    const float* g1  = (const float*)d_in[5];
    const float* be1 = (const float*)d_in[6];
    const float* g2  = (const float*)d_in[7];
    const float* be2 = (const float*)d_in[8];
    float* out = (float*)d_out;

    const int M = in_sizes[0] / H_DIM;   // 8192

    char* ws = (char*)d_ws;
    bf16_t* W1b = (bf16_t*)(ws);
    bf16_t* W2b = (bf16_t*)(ws + (8u << 20));
    bf16_t* lnb = (bf16_t*)(ws + (16u << 20));
    bf16_t* h1  = (bf16_t*)(ws + (48u << 20));
    const bool use_xb = ws_size >= ((size_t)96 << 20);
    bf16_t* xb  = use_xb ? (bf16_t*)(ws + (80u << 20)) : nullptr;

    const int n4tot = 2 * (H_DIM * H_DIM) / 4;
    cast2_kernel<<<dim3(n4tot / 256), dim3(256), 0, stream>>>(W1, W2, W1b, W2b);

    ln_f32_v2<<<dim3(M / 4), dim3(256), 0, stream>>>(x, g1, be1, lnb, xb);

    gemm8_kernel<0, 0><<<dim3((M / 256) * 8), dim3(512), 0, stream>>>(
        lnb, W1b, b1, nullptr, nullptr, h1, nullptr);

    ln_bf16_v2<<<dim3(M / 4), dim3(256), 0, stream>>>(h1, g2, be2, lnb);

    if (use_xb) {
        gemm8_kernel<1, 1><<<dim3((M / 256) * 8), dim3(512), 0, stream>>>(
            lnb, W2b, b2, nullptr, xb, nullptr, out);
    } else {
        gemm8_kernel<1, 0><<<dim3((M / 256) * 8), dim3(512), 0, stream>>>(
            lnb, W2b, b2, x, nullptr, nullptr, out);
    }
}

// Round 5
// 296.989 us; speedup vs baseline: 1.3303x; 1.0192x over previous
//
#include <hip/hip_runtime.h>
#include <hip/hip_bf16.h>

#define H_DIM 2048
#define LN_EPS 1e-5f

typedef __bf16 bf16_t;
typedef __bf16 bf16x4 __attribute__((ext_vector_type(4)));
typedef __bf16 bf16x8 __attribute__((ext_vector_type(8)));
typedef float f32x4 __attribute__((ext_vector_type(4)));

__device__ __forceinline__ void async_copy16(const void* g, void* l) {
    __builtin_amdgcn_global_load_lds((const __attribute__((address_space(1))) void*)g,
                                     (__attribute__((address_space(3))) void*)l,
                                     16, 0, 0);
}

#define FENCE() asm volatile("" ::: "memory")
#define BARRIER() do { FENCE(); __builtin_amdgcn_s_barrier(); FENCE(); } while (0)

// ---------------- fused: weight cast (blocks 0..8191) + LN1 (8192..10239) --
__global__ __launch_bounds__(256) void pre_kernel(const float* __restrict__ w1,
                                                  const float* __restrict__ w2,
                                                  bf16_t* __restrict__ o1,
                                                  bf16_t* __restrict__ o2,
                                                  const float* __restrict__ x,
                                                  const float* __restrict__ g,
                                                  const float* __restrict__ b,
                                                  bf16_t* __restrict__ lnb,
                                                  bf16_t* __restrict__ xb) {
    const int bid = blockIdx.x, t = threadIdx.x;
    if (bid < 8192) {
        const int n4 = (H_DIM * H_DIM) / 4;
        int i = bid * 256 + t;
        const float* src; bf16_t* dst; int j;
        if (i < n4) { src = w1; dst = o1; j = i; }
        else        { src = w2; dst = o2; j = i - n4; }
        float4 v = reinterpret_cast<const float4*>(src)[j];
        bf16x4 r;
        r[0] = (bf16_t)v.x; r[1] = (bf16_t)v.y; r[2] = (bf16_t)v.z; r[3] = (bf16_t)v.w;
        reinterpret_cast<bf16x4*>(dst)[j] = r;
        return;
    }
    // LayerNorm: one wave per row
    const int l = t & 63, w = t >> 6;
    const size_t row = (size_t)(bid - 8192) * 4 + w;
    const float* xr = x + row * H_DIM;
    float4 v[8];
    #pragma unroll
    for (int k = 0; k < 8; ++k) v[k] = reinterpret_cast<const float4*>(xr)[l + k * 64];
    float s = 0.f, s2 = 0.f;
    #pragma unroll
    for (int k = 0; k < 8; ++k) {
        s  += v[k].x + v[k].y + v[k].z + v[k].w;
        s2 += v[k].x * v[k].x + v[k].y * v[k].y + v[k].z * v[k].z + v[k].w * v[k].w;
    }
    #pragma unroll
    for (int off = 32; off > 0; off >>= 1) {
        s  += __shfl_down(s,  off, 64);
        s2 += __shfl_down(s2, off, 64);
    }
    s  = __shfl(s,  0, 64);
    s2 = __shfl(s2, 0, 64);
    float mu   = s * (1.f / H_DIM);
    float rstd = rsqrtf(s2 * (1.f / H_DIM) - mu * mu + LN_EPS);
    bf16_t* orow = lnb + row * H_DIM;
    bf16_t* xrow = xb ? xb + row * H_DIM : nullptr;
    #pragma unroll
    for (int k = 0; k < 8; ++k) {
        int c = l + k * 64;
        float4 gv = reinterpret_cast<const float4*>(g)[c];
        float4 bv = reinterpret_cast<const float4*>(b)[c];
        bf16x4 y;
        y[0] = (bf16_t)((v[k].x - mu) * rstd * gv.x + bv.x);
        y[1] = (bf16_t)((v[k].y - mu) * rstd * gv.y + bv.y);
        y[2] = (bf16_t)((v[k].z - mu) * rstd * gv.z + bv.z);
        y[3] = (bf16_t)((v[k].w - mu) * rstd * gv.w + bv.w);
        reinterpret_cast<bf16x4*>(orow)[c] = y;
        if (xrow) {
            bf16x4 xv;
            xv[0] = (bf16_t)v[k].x; xv[1] = (bf16_t)v[k].y;
            xv[2] = (bf16_t)v[k].z; xv[3] = (bf16_t)v[k].w;
            reinterpret_cast<bf16x4*>(xrow)[c] = xv;
        }
    }
}

// ---------------- LayerNorm, bf16 input -> bf16 output --------------------
__global__ __launch_bounds__(256) void ln_bf16_v2(const bf16_t* __restrict__ in,
                                                  const float* __restrict__ g,
                                                  const float* __restrict__ b,
                                                  bf16_t* __restrict__ out) {
    const int l = threadIdx.x & 63, w = threadIdx.x >> 6;
    const size_t row = (size_t)blockIdx.x * 4 + w;
    const bf16_t* xr = in + row * H_DIM;
    bf16x8 xv[4];
    #pragma unroll
    for (int k = 0; k < 4; ++k) xv[k] = reinterpret_cast<const bf16x8*>(xr)[l + k * 64];
    float vv[32];
    #pragma unroll
    for (int k = 0; k < 4; ++k)
        #pragma unroll
        for (int j = 0; j < 8; ++j) vv[k * 8 + j] = (float)xv[k][j];
    float s = 0.f, s2 = 0.f;
    #pragma unroll
    for (int e = 0; e < 32; ++e) { s += vv[e]; s2 += vv[e] * vv[e]; }
    #pragma unroll
    for (int off = 32; off > 0; off >>= 1) {
        s  += __shfl_down(s,  off, 64);
        s2 += __shfl_down(s2, off, 64);
    }
    s  = __shfl(s,  0, 64);
    s2 = __shfl(s2, 0, 64);
    float mu   = s * (1.f / H_DIM);
    float rstd = rsqrtf(s2 * (1.f / H_DIM) - mu * mu + LN_EPS);
    bf16_t* orow = out + row * H_DIM;
    #pragma unroll
    for (int k = 0; k < 4; ++k) {
        int c = l + k * 64;
        float4 g0 = reinterpret_cast<const float4*>(g)[c * 2];
        float4 g1 = reinterpret_cast<const float4*>(g)[c * 2 + 1];
        float4 b0 = reinterpret_cast<const float4*>(b)[c * 2];
        float4 b1 = reinterpret_cast<const float4*>(b)[c * 2 + 1];
        bf16x8 y;
        y[0] = (bf16_t)((vv[k*8+0] - mu) * rstd * g0.x + b0.x);
        y[1] = (bf16_t)((vv[k*8+1] - mu) * rstd * g0.y + b0.y);
        y[2] = (bf16_t)((vv[k*8+2] - mu) * rstd * g0.z + b0.z);
        y[3] = (bf16_t)((vv[k*8+3] - mu) * rstd * g0.w + b0.w);
        y[4] = (bf16_t)((vv[k*8+4] - mu) * rstd * g1.x + b1.x);
        y[5] = (bf16_t)((vv[k*8+5] - mu) * rstd * g1.y + b1.y);
        y[6] = (bf16_t)((vv[k*8+6] - mu) * rstd * g1.z + b1.z);
        y[7] = (bf16_t)((vv[k*8+7] - mu) * rstd * g1.w + b1.w);
        reinterpret_cast<bf16x8*>(orow)[c] = y;
    }
}

// ---------------- 256x256 8-wave bf16 GEMM (B^T), 2 windows / K-tile ------
#define LDW 88    // gemm<0> bounce pitch
#define RPW 264   // resid bounce pitch (528B rows: 16B-aligned, 4-way max)

template<int FINAL, int RB>
__global__ __launch_bounds__(512, 2) void gemm8_kernel(
    const bf16_t* __restrict__ A,
    const bf16_t* __restrict__ B,
    const float*  __restrict__ bias,
    const float*  __restrict__ residf,
    const bf16_t* __restrict__ residb,
    bf16_t* __restrict__ obf,
    float*  __restrict__ of)
{
    __shared__ bf16_t sm[8 * 8192];   // 128 KiB

    const int tid = threadIdx.x;
    const int l  = tid & 63, w = tid >> 6;
    const int wm = w >> 2,  wn = w & 3;
    const int cl = l & 15,  ch = l >> 4;

    const int cpx = gridDim.x >> 3;
    const int bid = blockIdx.x;
    const int swz = (bid & 7) * cpx + (bid >> 3);
    const size_t row0 = (size_t)(swz >> 3) * 256;
    const size_t col0 = (size_t)(swz & 7) * 256;

    const bf16_t* Abase = A + row0 * H_DIM;
    const bf16_t* Bbase = B + col0 * H_DIM;

    const int rr  = w * 8 + (l >> 3);
    const int scb = (l & 7) ^ (l >> 3);
    const size_t soff  = (size_t)rr * H_DIM + scb * 8;
    const int ldsw0 = w * 512;
    const int ldsw1 = 4096 + w * 512;

    const int swx = cl & 7;
    const int cbks[2] = { ch ^ swx, (4 + ch) ^ swx };

    // hoisted bias (4 values per lane)
    float bv[4];
    #pragma unroll
    for (int n = 0; n < 4; ++n) bv[n] = bias[col0 + wn * 64 + n * 16 + cl];

    f32x4 acc[2][4][4] = {};

    auto STAGE = [&](const bf16_t* Gb, int kt, int half, int region) {
        const bf16_t* g = Gb + (size_t)half * (128 * H_DIM) + kt * 64 + soff;
        bf16_t* s = &sm[region * 8192];
        async_copy16(g,               s + ldsw0);
        async_copy16(g + 64 * H_DIM,  s + ldsw1);
    };
    auto RDA = [&](int buf, int mh, int m, int ks) -> bf16x8 {
        int r = mh * 64 + m * 16 + cl;
        return *(const bf16x8*)&sm[(buf * 4 + wm) * 8192 + r * 64 + cbks[ks] * 8];
    };
    auto RDB = [&](int buf, int n, int ks) -> bf16x8 {
        int r = (wn & 1) * 64 + n * 16 + cl;
        return *(const bf16x8*)&sm[(buf * 4 + 2 + (wn >> 1)) * 8192 + r * 64 + cbks[ks] * 8];
    };

    // KT: 2 windows per K-tile, 32 MFMA per burst. buf literal at call sites.
    auto KT = [&](int buf, int t, bool stA, bool stB, int vm) {
        bf16x8 a0[4], a1[4], b0[4], b1[4];
        // W1: read all B (8) + A(mh0) both ks (8); stage A(t+1) h0+h1
        #pragma unroll
        for (int n = 0; n < 4; ++n) { b0[n] = RDB(buf, n, 0); b1[n] = RDB(buf, n, 1); }
        #pragma unroll
        for (int m = 0; m < 4; ++m) { a0[m] = RDA(buf, 0, m, 0); a1[m] = RDA(buf, 0, m, 1); }
        if (stA) { STAGE(Abase, t + 1, 0, (buf ^ 1) * 4 + 0);
                   STAGE(Abase, t + 1, 1, (buf ^ 1) * 4 + 1); }
        BARRIER();
        __builtin_amdgcn_s_setprio(1);
        #pragma unroll
        for (int m = 0; m < 4; ++m)
            #pragma unroll
            for (int n = 0; n < 4; ++n)
                acc[0][m][n] = __builtin_amdgcn_mfma_f32_16x16x32_bf16(a0[m], b0[n], acc[0][m][n], 0, 0, 0);
        #pragma unroll
        for (int m = 0; m < 4; ++m)
            #pragma unroll
            for (int n = 0; n < 4; ++n)
                acc[0][m][n] = __builtin_amdgcn_mfma_f32_16x16x32_bf16(a1[m], b1[n], acc[0][m][n], 0, 0, 0);
        __builtin_amdgcn_s_setprio(0);
        BARRIER();
        // W2: read A(mh1) both ks (8); stage B(t+2) h0+h1; counted vmcnt
        #pragma unroll
        for (int m = 0; m < 4; ++m) { a0[m] = RDA(buf, 1, m, 0); a1[m] = RDA(buf, 1, m, 1); }
        if (stB) { STAGE(Bbase, t + 2, 0, buf * 4 + 2);
                   STAGE(Bbase, t + 2, 1, buf * 4 + 3); }
        BARRIER();
        __builtin_amdgcn_s_setprio(1);
        #pragma unroll
        for (int m = 0; m < 4; ++m)
            #pragma unroll
            for (int n = 0; n < 4; ++n)
                acc[1][m][n] = __builtin_amdgcn_mfma_f32_16x16x32_bf16(a0[m], b0[n], acc[1][m][n], 0, 0, 0);
        #pragma unroll
        for (int m = 0; m < 4; ++m)
            #pragma unroll
            for (int n = 0; n < 4; ++n)
                acc[1][m][n] = __builtin_amdgcn_mfma_f32_16x16x32_bf16(a1[m], b1[n], acc[1][m][n], 0, 0, 0);
        __builtin_amdgcn_s_setprio(0);
        if (vm == 4)      asm volatile("s_waitcnt vmcnt(4)");
        else if (vm == 0) asm volatile("s_waitcnt vmcnt(0)");
        BARRIER();
    };

    // prologue
    STAGE(Abase, 0, 0, 0); STAGE(Abase, 0, 1, 1);
    STAGE(Bbase, 0, 0, 2); STAGE(Bbase, 0, 1, 3);
    STAGE(Bbase, 1, 0, 6); STAGE(Bbase, 1, 1, 7);
    asm volatile("s_waitcnt vmcnt(4)");
    BARRIER();

    for (int t = 0; t < 30; t += 2) {
        KT(0, t,     true, true, 4);
        KT(1, t + 1, true, true, 4);
    }
    KT(0, 30, true,  false, 0);
    KT(1, 31, false, false, -1);

    // epilogue
    if constexpr (FINAL) {
        if constexpr (RB) {
            // 2-pass resid bounce: pass p covers rows {q*128 + p*64 + s}
            #pragma unroll
            for (int p = 0; p < 2; ++p) {
                #pragma unroll
                for (int i = 0; i < 8; ++i) {
                    int c = i * 512 + tid;               // 4096 chunks of 8 elems
                    int u = c >> 5, cb = c & 31;
                    size_t gr = row0 + (size_t)(u >> 6) * 128 + p * 64 + (u & 63);
                    bf16x8 vv = *(const bf16x8*)&residb[gr * H_DIM + col0 + cb * 8];
                    *(bf16x8*)&sm[u * RPW + cb * 8] = vv;
                }
                BARRIER();
                #pragma unroll
                for (int m = 0; m < 4; ++m)
                    #pragma unroll
                    for (int n = 0; n < 4; ++n) {
                        size_t col = col0 + wn * 64 + n * 16 + cl;
                        #pragma unroll
                        for (int j = 0; j < 4; ++j) {
                            int u = wm * 64 + m * 16 + ch * 4 + j;
                            size_t row = row0 + wm * 128 + p * 64 + m * 16 + ch * 4 + j;
                            float rv = (float)sm[u * RPW + wn * 64 + n * 16 + cl];
                            of[row * H_DIM + col] = fmaxf(acc[p][m][n][j] + bv[n] + rv, 0.f);
                        }
                    }
                BARRIER();
            }
        } else {
            #pragma unroll
            for (int mh = 0; mh < 2; ++mh)
                #pragma unroll
                for (int m = 0; m < 4; ++m)
                    #pragma unroll
                    for (int n = 0; n < 4; ++n) {
                        size_t col = col0 + wn * 64 + n * 16 + cl;
                        #pragma unroll
                        for (int j = 0; j < 4; ++j) {
                            size_t row = row0 + wm * 128 + mh * 64 + m * 16 + ch * 4 + j;
                            size_t idx = row * H_DIM + col;
                            of[idx] = fmaxf(acc[mh][m][n][j] + bv[n] + residf[idx], 0.f);
                        }
                    }
        }
    } else {
        // coalesced bf16 store via per-wave LDS bounce
        bf16_t* wls = (bf16_t*)((char*)sm + w * (64 * LDW * 2));
        #pragma unroll
        for (int mh = 0; mh < 2; ++mh) {
            #pragma unroll
            for (int m = 0; m < 4; ++m)
                #pragma unroll
                for (int n = 0; n < 4; ++n)
                    #pragma unroll
                    for (int j = 0; j < 4; ++j) {
                        int lr = m * 16 + ch * 4 + j;
                        int lc = n * 16 + cl;
                        wls[lr * LDW + lc] = (bf16_t)fmaxf(acc[mh][m][n][j] + bv[n], 0.f);
                    }
            #pragma unroll
            for (int k = 0; k < 8; ++k) {
                int c = l + k * 64;
                int r = c >> 3, cb = c & 7;
                bf16x8 vv = *(const bf16x8*)&wls[r * LDW + cb * 8];
                size_t grow = row0 + wm * 128 + mh * 64 + r;
                *(bf16x8*)&obf[grow * H_DIM + col0 + wn * 64 + cb * 8] = vv;
            }
        }
    }
}

extern "C" void kernel_launch(void* const* d_in, const int* in_sizes, int n_in,
                              void* d_out, int out_size, void* d_ws, size_t ws_size,
                              hipStream_t stream) {
    const float* x   = (const float*)d_in[0];
    const float* W1  = (const float*)d_in[1];
    const float* b1  = (const float*)d_in[2];
    const float* W2  = (const float*)d_in[3];
    const float* b2  = (const float*)d_in[4];
    const float* g1  = (const float*)d_in[5];
    const float* be1 = (const float*)d_in[6];
    const float* g2  = (const float*)d_in[7];
    const float* be2 = (const float*)d_in[8];
    float* out = (float*)d_out;

    const int M = in_sizes[0] / H_DIM;   // 8192

    char* ws = (char*)d_ws;
    bf16_t* W1b = (bf16_t*)(ws);
    bf16_t* W2b = (bf16_t*)(ws + (8u << 20));
    bf16_t* lnb = (bf16_t*)(ws + (16u << 20));
    bf16_t* h1  = (bf16_t*)(ws + (48u << 20));
    const bool use_xb = ws_size >= ((size_t)96 << 20);
    bf16_t* xb  = use_xb ? (bf16_t*)(ws + (80u << 20)) : nullptr;

    pre_kernel<<<dim3(8192 + M / 4), dim3(256), 0, stream>>>(
        W1, W2, W1b, W2b, x, g1, be1, lnb, xb);

    gemm8_kernel<0, 0><<<dim3((M / 256) * 8), dim3(512), 0, stream>>>(
        lnb, W1b, b1, nullptr, nullptr, h1, nullptr);

    ln_bf16_v2<<<dim3(M / 4), dim3(256), 0, stream>>>(h1, g2, be2, lnb);

    if (use_xb) {
        gemm8_kernel<1, 1><<<dim3((M / 256) * 8), dim3(512), 0, stream>>>(
            lnb, W2b, b2, nullptr, xb, nullptr, out);
    } else {
        gemm8_kernel<1, 0><<<dim3((M / 256) * 8), dim3(512), 0, stream>>>(
            lnb, W2b, b2, x, nullptr, nullptr, out);
    }
}